// Round 3
// baseline (368.279 us; speedup 1.0000x reference)
//
#include <hip/hip_runtime.h>

namespace {
constexpr int kBB = 64, kH = 64, kW = 64, kC = 128, kP = 64;
constexpr int kHW = kH * kW;                 // 4096
constexpr long kRows = (long)kBB * kHW;      // 262144
constexpr long kOutElems = kRows * kC;       // 33554432

typedef float f4 __attribute__((ext_vector_type(4)));  // native vec for nontemporal builtins

// Fused: per 64-row block
//   (a) out[row][c] = sum_p s[row][p] * k[p][c]
//       k staged in LDS (32 KB, read from L2 once per block, then 69 TB/s LDS);
//       s read straight from global as a 2-address-per-wave broadcast — the
//       16 KB tile stays L1-hot, so no s_lds and no staging pass. LDS total
//       36.9 KB -> 4 blocks/CU (round-0 was 52.5 KB -> 2-3 blocks/CU).
//   (b) partial zsum[b][c] += sum_rows z[row][c], z2[b] += sum z^2 (atomics
//       after the GEMM, off the critical path). z is read-once -> nontemporal.
__global__ __launch_bounds__(256, 4) void fused_kernel(const float* __restrict__ z,
                                                       const float* __restrict__ s,
                                                       const float* __restrict__ kmat,
                                                       float* __restrict__ out,
                                                       float* __restrict__ zsum,
                                                       float* __restrict__ z2) {
  __shared__ f4 k_lds[kP][kC / 4];   // 32 KB
  __shared__ f4 red[8][32];          // 4 KB (z column partials)
  __shared__ float qred[4];

  const int t = threadIdx.x;
  const int cq = t & 31;   // float4-column 0..31
  const int tg = t >> 5;   // row-group 0..7
  const long rowbase = (long)blockIdx.x * 64;
  const int b = (int)(rowbase >> 12);    // 4096 rows per batch image

  // ---- stage k into LDS (32 KB; L2-resident after first touch) ----
  const f4* k4 = reinterpret_cast<const f4*>(kmat);
  f4* k_flat = &k_lds[0][0];
#pragma unroll
  for (int i = 0; i < 8; ++i) k_flat[t + 256 * i] = k4[t + 256 * i];

  // ---- stream this block's 64 z rows (read-once -> nontemporal) ----
  const f4* z4 = reinterpret_cast<const f4*>(z + rowbase * kC);
  float sx = 0.f, sy = 0.f, sz = 0.f, sw = 0.f, q = 0.f;
#pragma unroll
  for (int j = 0; j < 8; ++j) {
    const f4 v = __builtin_nontemporal_load(&z4[(tg + 8 * j) * 32 + cq]);
    sx += v.x; sy += v.y; sz += v.z; sw += v.w;
    q += v.x * v.x + v.y * v.y + v.z * v.z + v.w * v.w;
  }
  red[tg][cq] = (f4){sx, sy, sz, sw};
  for (int off = 32; off > 0; off >>= 1) q += __shfl_down(q, off, 64);
  if ((t & 63) == 0) qred[t >> 6] = q;

  __syncthreads();  // covers k staging + red/qred

  // ---- GEMM: each thread 8 rows x 1 float4 of c ----
  // s[row][4pc..4pc+3] is one f4 whose address is identical for all 32 lanes
  // of a half-wave -> L1 broadcast; the block's s tile (16 KB) stays L1-hot.
  const f4* s4 = reinterpret_cast<const f4*>(s + rowbase * kP);  // row stride 16 f4
  f4 acc[8];
#pragma unroll
  for (int j = 0; j < 8; ++j) acc[j] = (f4){0.f, 0.f, 0.f, 0.f};

#pragma unroll 2
  for (int pc = 0; pc < 16; ++pc) {  // p in chunks of 4
    const f4 k0 = k_lds[4 * pc + 0][cq];
    const f4 k1 = k_lds[4 * pc + 1][cq];
    const f4 k2 = k_lds[4 * pc + 2][cq];
    const f4 k3 = k_lds[4 * pc + 3][cq];
#pragma unroll
    for (int j = 0; j < 8; ++j) {
      const f4 sv = s4[(tg + 8 * j) * 16 + pc];  // broadcast load, L1-hot
      acc[j].x += sv.x * k0.x + sv.y * k1.x + sv.z * k2.x + sv.w * k3.x;
      acc[j].y += sv.x * k0.y + sv.y * k1.y + sv.z * k2.y + sv.w * k3.y;
      acc[j].z += sv.x * k0.z + sv.y * k1.z + sv.z * k2.z + sv.w * k3.z;
      acc[j].w += sv.x * k0.w + sv.y * k1.w + sv.z * k2.w + sv.w * k3.w;
    }
  }

  f4* out4 = reinterpret_cast<f4*>(out + rowbase * kC);
#pragma unroll
  for (int j = 0; j < 8; ++j)
    __builtin_nontemporal_store(acc[j], &out4[(tg + 8 * j) * 32 + cq]);

  // ---- finish z reduction AFTER the GEMM: 32 lanes fold 8 row-groups ----
  if (tg == 0) {
    f4 tot = red[0][cq];
#pragma unroll
    for (int j = 1; j < 8; ++j) {
      const f4 v = red[j][cq];
      tot.x += v.x; tot.y += v.y; tot.z += v.z; tot.w += v.w;
    }
    atomicAdd(&zsum[b * kC + cq * 4 + 0], tot.x);
    atomicAdd(&zsum[b * kC + cq * 4 + 1], tot.y);
    atomicAdd(&zsum[b * kC + cq * 4 + 2], tot.z);
    atomicAdd(&zsum[b * kC + cq * 4 + 3], tot.w);
    if (cq == 0) atomicAdd(&z2[b], qred[0] + qred[1] + qred[2] + qred[3]);
  }
}

// distance[b][p] = z2[b] - 2*dot(zsum[b],k[p]) + 4096*||k[p]||^2
__global__ __launch_bounds__(256) void dist_kernel(const float* __restrict__ zsum,
                                                   const float* __restrict__ z2,
                                                   const float* __restrict__ kmat,
                                                   float* __restrict__ dist) {
  const int g = blockIdx.x * 256 + threadIdx.x;  // 0..4095
  const int b = g >> 6;
  const int p = g & 63;
  const f4* zs4 = reinterpret_cast<const f4*>(zsum + b * kC);
  const f4* k4 = reinterpret_cast<const f4*>(kmat + p * kC);
  float dot = 0.f, k2 = 0.f;
#pragma unroll 8
  for (int i = 0; i < kC / 4; ++i) {
    const f4 kk = k4[i];
    const f4 zz = zs4[i];
    dot += zz.x * kk.x + zz.y * kk.y + zz.z * kk.z + zz.w * kk.w;
    k2 += kk.x * kk.x + kk.y * kk.y + kk.z * kk.z + kk.w * kk.w;
  }
  dist[g] = z2[b] - 2.f * dot + (float)kHW * k2;
}

}  // namespace

extern "C" void kernel_launch(void* const* d_in, const int* in_sizes, int n_in,
                              void* d_out, int out_size, void* d_ws, size_t ws_size,
                              hipStream_t stream) {
  const float* z = (const float*)d_in[0];      // (64,64,64,128)
  const float* s = (const float*)d_in[1];      // (64,64,64,64)
  const float* kmat = (const float*)d_in[2];   // (64,1,1,128)

  float* out = (float*)d_out;                  // 33554432 floats
  float* dist = out + kOutElems;               // 4096 floats

  float* zsum = (float*)d_ws;                  // 64*128 floats
  float* z2 = zsum + kBB * kC;                 // 64 floats

  // zero the atomic accumulators (ws is poisoned 0xAA each call)
  (void)hipMemsetAsync(d_ws, 0, (size_t)(kBB * kC + kBB) * sizeof(float), stream);

  fused_kernel<<<(int)(kRows / 64), 256, 0, stream>>>(z, s, kmat, out, zsum, z2);
  dist_kernel<<<16, 256, 0, stream>>>(zsum, z2, kmat, dist);
}

// Round 5
// 296.067 us; speedup vs baseline: 1.2439x; 1.2439x over previous
//
#include <hip/hip_runtime.h>

namespace {
constexpr int kBB = 64, kH = 64, kW = 64, kC = 128, kP = 64;
constexpr int kHW = kH * kW;                 // 4096
constexpr long kRows = (long)kBB * kHW;      // 262144
constexpr long kOutElems = kRows * kC;       // 33554432

typedef float f4 __attribute__((ext_vector_type(4)));  // native vec for nontemporal builtins

// Fused: per 64-row block
//   (a) out[row][c] = sum_p s[row][p] * k[p][c]  — round-0 inner loop (k strided
//       from LDS, s broadcast from LDS: proven 43 µs total VALU issue), but k is
//       staged in HALVES (16 KB) so LDS/block = 36.4 KB -> 4 blocks/CU resident
//       (round 0: 52.5 KB -> 2). Second k half is prefetched into registers
//       BEFORE GEMM-A so its L2 latency hides under ~2000 FMA cycles.
//   (b) partial zsum[b][c] += sum_rows z[row][c], z2[b] += sum z^2 (atomics).
//       z/s/out are touched exactly once -> nontemporal, keeps k hot in cache.
__global__ __launch_bounds__(256, 4) void fused_kernel(const float* __restrict__ z,
                                                       const float* __restrict__ s,
                                                       const float* __restrict__ kmat,
                                                       float* __restrict__ out,
                                                       float* __restrict__ zsum,
                                                       float* __restrict__ z2) {
  __shared__ f4 k_lds[32][kC / 4];   // 16 KB — one half of k (32 p-rows)
  __shared__ f4 s_lds[64][kP / 4];   // 16 KB
  __shared__ f4 red[8][32];          // 4 KB (z column partials)
  __shared__ float qred[4];

  const int t = threadIdx.x;
  const int cq = t & 31;   // float4-column 0..31
  const int tg = t >> 5;   // row-group 0..7
  const long rowbase = (long)blockIdx.x * 64;
  const int b = (int)(rowbase >> 12);    // 4096 rows per batch image

  // ---- stage k first half (p=0..31, 16 KB; L2-resident after first touch) ----
  const f4* k4g = reinterpret_cast<const f4*>(kmat);
  f4* k_flat = &k_lds[0][0];
#pragma unroll
  for (int i = 0; i < 4; ++i) k_flat[t + 256 * i] = k4g[t + 256 * i];

  // ---- stage s tile (16 KB, read-once -> nontemporal) ----
  const f4* s4 = reinterpret_cast<const f4*>(s + rowbase * kP);
  f4* s_flat = &s_lds[0][0];
#pragma unroll
  for (int i = 0; i < 4; ++i)
    s_flat[t + 256 * i] = __builtin_nontemporal_load(&s4[t + 256 * i]);

  // ---- stream this block's 64 z rows (read-once -> nontemporal) ----
  const f4* z4 = reinterpret_cast<const f4*>(z + rowbase * kC);
  float sx = 0.f, sy = 0.f, sz = 0.f, sw = 0.f, q = 0.f;
#pragma unroll
  for (int j = 0; j < 8; ++j) {
    const f4 v = __builtin_nontemporal_load(&z4[(tg + 8 * j) * 32 + cq]);
    sx += v.x; sy += v.y; sz += v.z; sw += v.w;
    q += v.x * v.x + v.y * v.y + v.z * v.z + v.w * v.w;
  }
  red[tg][cq] = (f4){sx, sy, sz, sw};
  for (int off = 32; off > 0; off >>= 1) q += __shfl_down(q, off, 64);
  if ((t & 63) == 0) qred[t >> 6] = q;

  // ---- prefetch k second half (p=32..63) into registers; latency hides
  //      under GEMM-A's ~2000 FMA cycles ----
  f4 kpre[4];
#pragma unroll
  for (int i = 0; i < 4; ++i) kpre[i] = k4g[1024 + t + 256 * i];

  __syncthreads();  // covers k-half-1 / s staging + red/qred

  f4 acc[8];
#pragma unroll
  for (int j = 0; j < 8; ++j) acc[j] = (f4){0.f, 0.f, 0.f, 0.f};

  // ---- GEMM-A: p = 0..31 ----
#pragma unroll 2
  for (int pc = 0; pc < 8; ++pc) {  // p in chunks of 4
    const f4 k0 = k_lds[4 * pc + 0][cq];
    const f4 k1 = k_lds[4 * pc + 1][cq];
    const f4 k2 = k_lds[4 * pc + 2][cq];
    const f4 k3 = k_lds[4 * pc + 3][cq];
#pragma unroll
    for (int j = 0; j < 8; ++j) {
      const f4 sv = s_lds[tg + 8 * j][pc];  // LDS broadcast across 32 lanes
      acc[j].x += sv.x * k0.x + sv.y * k1.x + sv.z * k2.x + sv.w * k3.x;
      acc[j].y += sv.x * k0.y + sv.y * k1.y + sv.z * k2.y + sv.w * k3.y;
      acc[j].z += sv.x * k0.z + sv.y * k1.z + sv.z * k2.z + sv.w * k3.z;
      acc[j].w += sv.x * k0.w + sv.y * k1.w + sv.z * k2.w + sv.w * k3.w;
    }
  }

  __syncthreads();  // everyone done reading k half 1
#pragma unroll
  for (int i = 0; i < 4; ++i) k_flat[t + 256 * i] = kpre[i];
  __syncthreads();  // k half 2 visible

  // ---- GEMM-B: p = 32..63 (s column pc = 8..15, k_lds row 4*(pc-8)+i) ----
#pragma unroll 2
  for (int pc = 8; pc < 16; ++pc) {
    const f4 k0 = k_lds[4 * (pc - 8) + 0][cq];
    const f4 k1 = k_lds[4 * (pc - 8) + 1][cq];
    const f4 k2 = k_lds[4 * (pc - 8) + 2][cq];
    const f4 k3 = k_lds[4 * (pc - 8) + 3][cq];
#pragma unroll
    for (int j = 0; j < 8; ++j) {
      const f4 sv = s_lds[tg + 8 * j][pc];
      acc[j].x += sv.x * k0.x + sv.y * k1.x + sv.z * k2.x + sv.w * k3.x;
      acc[j].y += sv.x * k0.y + sv.y * k1.y + sv.z * k2.y + sv.w * k3.y;
      acc[j].z += sv.x * k0.z + sv.y * k1.z + sv.z * k2.z + sv.w * k3.z;
      acc[j].w += sv.x * k0.w + sv.y * k1.w + sv.z * k2.w + sv.w * k3.w;
    }
  }

  f4* out4 = reinterpret_cast<f4*>(out + rowbase * kC);
#pragma unroll
  for (int j = 0; j < 8; ++j)
    __builtin_nontemporal_store(acc[j], &out4[(tg + 8 * j) * 32 + cq]);

  // ---- finish z reduction: 32 lanes fold 8 row-groups, atomics into ws ----
  if (tg == 0) {
    f4 tot = red[0][cq];
#pragma unroll
    for (int j = 1; j < 8; ++j) {
      const f4 v = red[j][cq];
      tot.x += v.x; tot.y += v.y; tot.z += v.z; tot.w += v.w;
    }
    atomicAdd(&zsum[b * kC + cq * 4 + 0], tot.x);
    atomicAdd(&zsum[b * kC + cq * 4 + 1], tot.y);
    atomicAdd(&zsum[b * kC + cq * 4 + 2], tot.z);
    atomicAdd(&zsum[b * kC + cq * 4 + 3], tot.w);
    if (cq == 0) atomicAdd(&z2[b], qred[0] + qred[1] + qred[2] + qred[3]);
  }
}

// distance[b][p] = z2[b] - 2*dot(zsum[b],k[p]) + 4096*||k[p]||^2
__global__ __launch_bounds__(256) void dist_kernel(const float* __restrict__ zsum,
                                                   const float* __restrict__ z2,
                                                   const float* __restrict__ kmat,
                                                   float* __restrict__ dist) {
  const int g = blockIdx.x * 256 + threadIdx.x;  // 0..4095
  const int b = g >> 6;
  const int p = g & 63;
  const f4* zs4 = reinterpret_cast<const f4*>(zsum + b * kC);
  const f4* k4 = reinterpret_cast<const f4*>(kmat + p * kC);
  float dot = 0.f, k2 = 0.f;
#pragma unroll 8
  for (int i = 0; i < kC / 4; ++i) {
    const f4 kk = k4[i];
    const f4 zz = zs4[i];
    dot += zz.x * kk.x + zz.y * kk.y + zz.z * kk.z + zz.w * kk.w;
    k2 += kk.x * kk.x + kk.y * kk.y + kk.z * kk.z + kk.w * kk.w;
  }
  dist[g] = z2[b] - 2.f * dot + (float)kHW * k2;
}

}  // namespace

extern "C" void kernel_launch(void* const* d_in, const int* in_sizes, int n_in,
                              void* d_out, int out_size, void* d_ws, size_t ws_size,
                              hipStream_t stream) {
  const float* z = (const float*)d_in[0];      // (64,64,64,128)
  const float* s = (const float*)d_in[1];      // (64,64,64,64)
  const float* kmat = (const float*)d_in[2];   // (64,1,1,128)

  float* out = (float*)d_out;                  // 33554432 floats
  float* dist = out + kOutElems;               // 4096 floats

  float* zsum = (float*)d_ws;                  // 64*128 floats
  float* z2 = zsum + kBB * kC;                 // 64 floats

  // zero the atomic accumulators (ws is poisoned 0xAA each call)
  (void)hipMemsetAsync(d_ws, 0, (size_t)(kBB * kC + kBB) * sizeof(float), stream);

  fused_kernel<<<(int)(kRows / 64), 256, 0, stream>>>(z, s, kmat, out, zsum, z2);
  dist_kernel<<<16, 256, 0, stream>>>(zsum, z2, kmat, dist);
}

// Round 6
// 294.044 us; speedup vs baseline: 1.2525x; 1.0069x over previous
//
#include <hip/hip_runtime.h>

namespace {
constexpr int kBB = 64, kH = 64, kW = 64, kC = 128, kP = 64;
constexpr int kHW = kH * kW;                 // 4096
constexpr long kRows = (long)kBB * kHW;      // 262144
constexpr long kOutElems = kRows * kC;       // 33554432

constexpr int kGemmTiles = (int)(kRows / 64); // 4096 tiles of 64 rows
constexpr int kZBlocks = 512;                 // each reduces 512 z rows (1/8 image)
constexpr int kGrid = kGemmTiles + kZBlocks;  // 4608, interleaved 8:1 by bid%9

typedef float f4 __attribute__((ext_vector_type(4)));  // native vec for nontemporal builtins

// Block-specialized fused kernel (producer/consumer at CU level):
//   bid%9 != 8 -> GEMM block: out[64 rows][128c] = s_tile * k. Full k (32 KB) +
//       s tile (16 KB) in LDS, ONE barrier, round-0's proven inner loop
//       (43 us total VALU issue). No z work -> FMA/LDS-bound.
//   bid%9 == 8 -> z block: pure streaming reduction of 512 z rows (nontemporal),
//       no LDS until the final 4 KB fold, no barrier until then -> HBM-bound.
// Both roles co-resident on every CU (3 blocks/CU at 48 KB LDS), so z's HBM
// stream overlaps GEMM's FMA at the wave scheduler instead of being a serial
// phase inside every block (round-5 showed phases summed, not maxed: 95 us
// ~= 27 FMA + 39 HBM + 20 LDS + barriers).
__global__ __launch_bounds__(256) void fused_kernel(const float* __restrict__ z,
                                                    const float* __restrict__ s,
                                                    const float* __restrict__ kmat,
                                                    float* __restrict__ out,
                                                    float* __restrict__ zsum,
                                                    float* __restrict__ z2) {
  __shared__ f4 k_lds[kP][kC / 4];   // 32 KB (z path: unused)
  __shared__ f4 s_lds[64][kP / 4];   // 16 KB (z path: reused as red[256] + qred)

  const int t = threadIdx.x;
  const int cq = t & 31;   // float4-column 0..31
  const int tg = t >> 5;   // row-group 0..7
  const int bid = blockIdx.x;
  const int r9 = bid % 9;

  if (r9 == 8) {
    // ================= z-reduction block: 512 rows, same batch image =========
    const int zi = bid / 9;                  // 0..511
    const long row0 = (long)zi * 512;
    const int b = (int)(row0 >> 12);         // 4096 rows per image -> 8 z-blocks/image
    const f4* z4 = reinterpret_cast<const f4*>(z + row0 * kC);

    f4 sum = (f4){0.f, 0.f, 0.f, 0.f};
    float q = 0.f;
#pragma unroll 8
    for (int i = 0; i < 64; ++i) {           // rows tg + 8*i
      const f4 v = __builtin_nontemporal_load(&z4[((long)(tg + 8 * i)) * 32 + cq]);
      sum += v;
      q += v.x * v.x + v.y * v.y + v.z * v.z + v.w * v.w;
    }

    f4* red = &s_lds[0][0];                  // 256 f4 = 4 KB
    float* qred = reinterpret_cast<float*>(&s_lds[16][0]);  // next 16 B
    red[tg * 32 + cq] = sum;
    for (int off = 32; off > 0; off >>= 1) q += __shfl_down(q, off, 64);
    if ((t & 63) == 0) qred[t >> 6] = q;
    __syncthreads();

    if (tg == 0) {
      f4 tot = red[cq];
#pragma unroll
      for (int j = 1; j < 8; ++j) tot += red[j * 32 + cq];
      atomicAdd(&zsum[b * kC + cq * 4 + 0], tot.x);
      atomicAdd(&zsum[b * kC + cq * 4 + 1], tot.y);
      atomicAdd(&zsum[b * kC + cq * 4 + 2], tot.z);
      atomicAdd(&zsum[b * kC + cq * 4 + 3], tot.w);
      if (cq == 0) atomicAdd(&z2[b], qred[0] + qred[1] + qred[2] + qred[3]);
    }
    return;
  }

  // ================= GEMM block: one 64-row tile ==============================
  const long tile = (long)(bid / 9) * 8 + r9;    // 0..4095
  const long rowbase = tile * 64;

  // stage full k (32 KB; L2-resident after first touch)
  const f4* k4g = reinterpret_cast<const f4*>(kmat);
  f4* k_flat = &k_lds[0][0];
#pragma unroll
  for (int i = 0; i < 8; ++i) k_flat[t + 256 * i] = k4g[t + 256 * i];

  // stage s tile (16 KB, read-once -> nontemporal)
  const f4* s4 = reinterpret_cast<const f4*>(s + rowbase * kP);
  f4* s_flat = &s_lds[0][0];
#pragma unroll
  for (int i = 0; i < 4; ++i)
    s_flat[t + 256 * i] = __builtin_nontemporal_load(&s4[t + 256 * i]);

  __syncthreads();  // single barrier

  f4 acc[8];
#pragma unroll
  for (int j = 0; j < 8; ++j) acc[j] = (f4){0.f, 0.f, 0.f, 0.f};

#pragma unroll 2
  for (int pc = 0; pc < 16; ++pc) {  // p in chunks of 4
    const f4 k0 = k_lds[4 * pc + 0][cq];
    const f4 k1 = k_lds[4 * pc + 1][cq];
    const f4 k2 = k_lds[4 * pc + 2][cq];
    const f4 k3 = k_lds[4 * pc + 3][cq];
#pragma unroll
    for (int j = 0; j < 8; ++j) {
      const f4 sv = s_lds[tg + 8 * j][pc];  // LDS broadcast across 32 lanes
      acc[j].x += sv.x * k0.x + sv.y * k1.x + sv.z * k2.x + sv.w * k3.x;
      acc[j].y += sv.x * k0.y + sv.y * k1.y + sv.z * k2.y + sv.w * k3.y;
      acc[j].z += sv.x * k0.z + sv.y * k1.z + sv.z * k2.z + sv.w * k3.z;
      acc[j].w += sv.x * k0.w + sv.y * k1.w + sv.z * k2.w + sv.w * k3.w;
    }
  }

  f4* out4 = reinterpret_cast<f4*>(out + rowbase * kC);
#pragma unroll
  for (int j = 0; j < 8; ++j)
    __builtin_nontemporal_store(acc[j], &out4[(tg + 8 * j) * 32 + cq]);
}

// distance[b][p] = z2[b] - 2*dot(zsum[b],k[p]) + 4096*||k[p]||^2
__global__ __launch_bounds__(256) void dist_kernel(const float* __restrict__ zsum,
                                                   const float* __restrict__ z2,
                                                   const float* __restrict__ kmat,
                                                   float* __restrict__ dist) {
  const int g = blockIdx.x * 256 + threadIdx.x;  // 0..4095
  const int b = g >> 6;
  const int p = g & 63;
  const f4* zs4 = reinterpret_cast<const f4*>(zsum + b * kC);
  const f4* k4 = reinterpret_cast<const f4*>(kmat + p * kC);
  float dot = 0.f, k2 = 0.f;
#pragma unroll 8
  for (int i = 0; i < kC / 4; ++i) {
    const f4 kk = k4[i];
    const f4 zz = zs4[i];
    dot += zz.x * kk.x + zz.y * kk.y + zz.z * kk.z + zz.w * kk.w;
    k2 += kk.x * kk.x + kk.y * kk.y + kk.z * kk.z + kk.w * kk.w;
  }
  dist[g] = z2[b] - 2.f * dot + (float)kHW * k2;
}

}  // namespace

extern "C" void kernel_launch(void* const* d_in, const int* in_sizes, int n_in,
                              void* d_out, int out_size, void* d_ws, size_t ws_size,
                              hipStream_t stream) {
  const float* z = (const float*)d_in[0];      // (64,64,64,128)
  const float* s = (const float*)d_in[1];      // (64,64,64,64)
  const float* kmat = (const float*)d_in[2];   // (64,1,1,128)

  float* out = (float*)d_out;                  // 33554432 floats
  float* dist = out + kOutElems;               // 4096 floats

  float* zsum = (float*)d_ws;                  // 64*128 floats
  float* z2 = zsum + kBB * kC;                 // 64 floats

  // zero the atomic accumulators (ws is poisoned 0xAA each call)
  (void)hipMemsetAsync(d_ws, 0, (size_t)(kBB * kC + kBB) * sizeof(float), stream);

  fused_kernel<<<kGrid, 256, 0, stream>>>(z, s, kmat, out, zsum, z2);
  dist_kernel<<<16, 256, 0, stream>>>(zsum, z2, kmat, dist);
}

// Round 7
// 288.645 us; speedup vs baseline: 1.2759x; 1.0187x over previous
//
#include <hip/hip_runtime.h>

namespace {
constexpr int kBB = 64, kH = 64, kW = 64, kC = 128, kP = 64;
constexpr int kHW = kH * kW;                 // 4096
constexpr long kRows = (long)kBB * kHW;      // 262144
constexpr long kOutElems = kRows * kC;       // 33554432

constexpr int kGemmTiles = (int)(kRows / 64); // 4096 tiles of 64 rows
constexpr int kZBlocks = 512;                 // each reduces 512 z rows (1/8 image)
constexpr int kGrid = kGemmTiles + kZBlocks;  // 4608, interleaved 8:1 by bid%9

typedef float f4 __attribute__((ext_vector_type(4)));  // native vec for nontemporal builtins

// Block-specialized + k-halved fused kernel.
//   GEMM blocks (bid%9 != 8): out[64r][128c] = s_tile * k. k staged in HALVES
//       (16 KB), half 2 register-prefetched before GEMM-A so its L2 latency
//       hides under ~2000 FMA cycles (proven round 5). LDS = 16+16 = 32 KB
//       exactly -> 5 blocks/CU (round 6's 48 KB gave 3 theoretical, 1.4
//       effective -> latency-bound at 46% VALU).
//   z blocks (bid%9 == 8): pure 512-row streaming reduction (HBM/L3-bound),
//       reuse the GEMM LDS buffers for the tiny fold.
// Roles interleave on every CU so z's memory stream overlaps GEMM's FMA.
__global__ __launch_bounds__(256) void fused_kernel(const float* __restrict__ z,
                                                    const float* __restrict__ s,
                                                    const float* __restrict__ kmat,
                                                    float* __restrict__ out,
                                                    float* __restrict__ zsum,
                                                    float* __restrict__ z2) {
  __shared__ f4 k_lds[32][kC / 4];   // 16 KB — one half of k (32 p-rows)
  __shared__ f4 s_lds[64][kP / 4];   // 16 KB — s tile (z path: red buffer)

  const int t = threadIdx.x;
  const int cq = t & 31;   // float4-column 0..31
  const int tg = t >> 5;   // row-group 0..7
  const int bid = blockIdx.x;
  const int r9 = bid % 9;

  if (r9 == 8) {
    // ================= z-reduction block: 512 rows, same batch image =========
    const int zi = bid / 9;                  // 0..511
    const long row0 = (long)zi * 512;
    const int b = (int)(row0 >> 12);         // 8 z-blocks per image
    const f4* z4 = reinterpret_cast<const f4*>(z + row0 * kC);

    f4 sum = (f4){0.f, 0.f, 0.f, 0.f};
    float q = 0.f;
#pragma unroll 8
    for (int i = 0; i < 64; ++i) {           // rows tg + 8*i
      const f4 v = __builtin_nontemporal_load(&z4[((long)(tg + 8 * i)) * 32 + cq]);
      sum += v;
      q += v.x * v.x + v.y * v.y + v.z * v.z + v.w * v.w;
    }

    f4* red = &s_lds[0][0];                  // 256 f4 = 4 KB
    float* qred = reinterpret_cast<float*>(&k_lds[0][0]);  // 16 B, k_lds unused
    red[tg * 32 + cq] = sum;
    for (int off = 32; off > 0; off >>= 1) q += __shfl_down(q, off, 64);
    if ((t & 63) == 0) qred[t >> 6] = q;
    __syncthreads();

    if (tg == 0) {
      f4 tot = red[cq];
#pragma unroll
      for (int j = 1; j < 8; ++j) tot += red[j * 32 + cq];
      atomicAdd(&zsum[b * kC + cq * 4 + 0], tot.x);
      atomicAdd(&zsum[b * kC + cq * 4 + 1], tot.y);
      atomicAdd(&zsum[b * kC + cq * 4 + 2], tot.z);
      atomicAdd(&zsum[b * kC + cq * 4 + 3], tot.w);
      if (cq == 0) atomicAdd(&z2[b], qred[0] + qred[1] + qred[2] + qred[3]);
    }
    return;
  }

  // ================= GEMM block: one 64-row tile ==============================
  const long tile = (long)(bid / 9) * 8 + r9;    // 0..4095
  const long rowbase = tile * 64;

  // stage k first half (p=0..31, 16 KB; L2-resident after first touch)
  const f4* k4g = reinterpret_cast<const f4*>(kmat);
  f4* k_flat = &k_lds[0][0];
#pragma unroll
  for (int i = 0; i < 4; ++i) k_flat[t + 256 * i] = k4g[t + 256 * i];

  // stage s tile (16 KB, read-once -> nontemporal)
  const f4* s4 = reinterpret_cast<const f4*>(s + rowbase * kP);
  f4* s_flat = &s_lds[0][0];
#pragma unroll
  for (int i = 0; i < 4; ++i)
    s_flat[t + 256 * i] = __builtin_nontemporal_load(&s4[t + 256 * i]);

  // prefetch k second half (p=32..63) into regs; latency hides under GEMM-A
  f4 kpre[4];
#pragma unroll
  for (int i = 0; i < 4; ++i) kpre[i] = k4g[1024 + t + 256 * i];

  __syncthreads();  // k-half-1 + s staged

  f4 acc[8];
#pragma unroll
  for (int j = 0; j < 8; ++j) acc[j] = (f4){0.f, 0.f, 0.f, 0.f};

  // ---- GEMM-A: p = 0..31 ----
#pragma unroll 2
  for (int pc = 0; pc < 8; ++pc) {  // p in chunks of 4
    const f4 k0 = k_lds[4 * pc + 0][cq];
    const f4 k1 = k_lds[4 * pc + 1][cq];
    const f4 k2 = k_lds[4 * pc + 2][cq];
    const f4 k3 = k_lds[4 * pc + 3][cq];
#pragma unroll
    for (int j = 0; j < 8; ++j) {
      const f4 sv = s_lds[tg + 8 * j][pc];  // LDS broadcast across 32 lanes
      acc[j].x += sv.x * k0.x + sv.y * k1.x + sv.z * k2.x + sv.w * k3.x;
      acc[j].y += sv.x * k0.y + sv.y * k1.y + sv.z * k2.y + sv.w * k3.y;
      acc[j].z += sv.x * k0.z + sv.y * k1.z + sv.z * k2.z + sv.w * k3.z;
      acc[j].w += sv.x * k0.w + sv.y * k1.w + sv.z * k2.w + sv.w * k3.w;
    }
  }

  __syncthreads();  // everyone done reading k half 1
#pragma unroll
  for (int i = 0; i < 4; ++i) k_flat[t + 256 * i] = kpre[i];
  __syncthreads();  // k half 2 visible

  // ---- GEMM-B: p = 32..63 (s column pc = 8..15, k_lds row 4*(pc-8)+i) ----
#pragma unroll 2
  for (int pc = 8; pc < 16; ++pc) {
    const f4 k0 = k_lds[4 * (pc - 8) + 0][cq];
    const f4 k1 = k_lds[4 * (pc - 8) + 1][cq];
    const f4 k2 = k_lds[4 * (pc - 8) + 2][cq];
    const f4 k3 = k_lds[4 * (pc - 8) + 3][cq];
#pragma unroll
    for (int j = 0; j < 8; ++j) {
      const f4 sv = s_lds[tg + 8 * j][pc];
      acc[j].x += sv.x * k0.x + sv.y * k1.x + sv.z * k2.x + sv.w * k3.x;
      acc[j].y += sv.x * k0.y + sv.y * k1.y + sv.z * k2.y + sv.w * k3.y;
      acc[j].z += sv.x * k0.z + sv.y * k1.z + sv.z * k2.z + sv.w * k3.z;
      acc[j].w += sv.x * k0.w + sv.y * k1.w + sv.z * k2.w + sv.w * k3.w;
    }
  }

  f4* out4 = reinterpret_cast<f4*>(out + rowbase * kC);
#pragma unroll
  for (int j = 0; j < 8; ++j)
    __builtin_nontemporal_store(acc[j], &out4[(tg + 8 * j) * 32 + cq]);
}

// distance[b][p] = z2[b] - 2*dot(zsum[b],k[p]) + 4096*||k[p]||^2
__global__ __launch_bounds__(256) void dist_kernel(const float* __restrict__ zsum,
                                                   const float* __restrict__ z2,
                                                   const float* __restrict__ kmat,
                                                   float* __restrict__ dist) {
  const int g = blockIdx.x * 256 + threadIdx.x;  // 0..4095
  const int b = g >> 6;
  const int p = g & 63;
  const f4* zs4 = reinterpret_cast<const f4*>(zsum + b * kC);
  const f4* k4 = reinterpret_cast<const f4*>(kmat + p * kC);
  float dot = 0.f, k2 = 0.f;
#pragma unroll 8
  for (int i = 0; i < kC / 4; ++i) {
    const f4 kk = k4[i];
    const f4 zz = zs4[i];
    dot += zz.x * kk.x + zz.y * kk.y + zz.z * kk.z + zz.w * kk.w;
    k2 += kk.x * kk.x + kk.y * kk.y + kk.z * kk.z + kk.w * kk.w;
  }
  dist[g] = z2[b] - 2.f * dot + (float)kHW * k2;
}

}  // namespace

extern "C" void kernel_launch(void* const* d_in, const int* in_sizes, int n_in,
                              void* d_out, int out_size, void* d_ws, size_t ws_size,
                              hipStream_t stream) {
  const float* z = (const float*)d_in[0];      // (64,64,64,128)
  const float* s = (const float*)d_in[1];      // (64,64,64,64)
  const float* kmat = (const float*)d_in[2];   // (64,1,1,128)

  float* out = (float*)d_out;                  // 33554432 floats
  float* dist = out + kOutElems;               // 4096 floats

  float* zsum = (float*)d_ws;                  // 64*128 floats
  float* z2 = zsum + kBB * kC;                 // 64 floats

  // zero the atomic accumulators (ws is poisoned 0xAA each call)
  (void)hipMemsetAsync(d_ws, 0, (size_t)(kBB * kC + kBB) * sizeof(float), stream);

  fused_kernel<<<kGrid, 256, 0, stream>>>(z, s, kmat, out, zsum, z2);
  dist_kernel<<<16, 256, 0, stream>>>(zsum, z2, kmat, dist);
}